// Round 1
// baseline (110.027 us; speedup 1.0000x reference)
//
#include <hip/hip_runtime.h>
#include <hip/hip_bf16.h>

// PositionalEmbedding: out[b,t,:] = tok_weight[x[b,t],:] + pos_weight[t,:]
// B=4, T=4096, E=512, fp32. Pure memory-bound gather+add.
//
// Layout math (all power-of-2):
//   E = 512 floats = 128 float4 per row
//   rows = B*T = 16384; flat float4 elements = 16384*128 = 2,097,152
//   row   = idx4 >> 7
//   col4  = idx4 & 127
//   t     = row & (T-1) = row & 4095
//   tok   = x[row]   (flat [B,T] int32)
//
// One float4 per thread: 16 B/lane coalesced loads/stores. Each gathered
// tok_weight row is 2 KB contiguous, so lanes within a wave stay coalesced
// even though rows are random.

#define TT 4096      // TIME / sequence length
#define EV4 128      // EMBED / 4

__global__ __launch_bounds__(256) void pos_embed_kernel(
    const int* __restrict__ x,            // [B*T]
    const float4* __restrict__ tok_w,     // [VOCAB, EV4]
    const float4* __restrict__ pos_w,     // [TT, EV4]
    float4* __restrict__ out,             // [B*T, EV4]
    int n4)                               // total float4 elements
{
    int idx = blockIdx.x * blockDim.x + threadIdx.x;
    if (idx >= n4) return;

    int row  = idx >> 7;          // which (b,t) row
    int col4 = idx & (EV4 - 1);   // float4 column within the row
    int t    = row & (TT - 1);    // position index

    int tok_row = x[row];

    float4 a = tok_w[(size_t)tok_row * EV4 + col4];
    float4 p = pos_w[(size_t)t * EV4 + col4];

    float4 r;
    r.x = a.x + p.x;
    r.y = a.y + p.y;
    r.z = a.z + p.z;
    r.w = a.w + p.w;

    out[idx] = r;
}

extern "C" void kernel_launch(void* const* d_in, const int* in_sizes, int n_in,
                              void* d_out, int out_size, void* d_ws, size_t ws_size,
                              hipStream_t stream) {
    const int*    x     = (const int*)d_in[0];      // [B,T] int32
    const float4* tok_w = (const float4*)d_in[1];   // [VOCAB, E] fp32
    const float4* pos_w = (const float4*)d_in[2];   // [T, E] fp32
    float4*       out   = (float4*)d_out;           // [B,T,E] fp32

    int n4 = out_size / 4;                          // 2,097,152 float4
    int block = 256;
    int grid  = (n4 + block - 1) / block;           // 8192 blocks

    pos_embed_kernel<<<grid, block, 0, stream>>>(x, tok_w, pos_w, out, n4);
}